// Round 13
// baseline (505.006 us; speedup 1.0000x reference)
//
#include <hip/hip_runtime.h>

// ---------------------------------------------------------------------------
// RPN forward, MI355X. Only batch element 7 contributes to the output.
// prepK (fused: zero-pad input 512x52x52 + weight->SGPR-layout transpose) ->
// conv3x3 v12 (thread = ADJACENT pixel pair (2q,2q+1): shared 3x4 window =
// 6 aligned float2 loads/cin (vs 18 scalar), 72 SGPR weights / 144 FMA per
// cin, immediate-offset loads, float2 stores, NO LDS) -> reduce_leaky4 ->
// 1x1 heads (k-split x3) -> decode/score/key (+rank zeroing) -> O(N^2) rank
// sort -> top-6000 -> NMS bitmask v2 (lane=j, ballot, NO LDS; reference's
// yy2=max bug replicated token-identically) -> PAIRED word-serial scan ->
// 300x4 boxes. Deterministic fp32: per-accumulator FMA chain (cin asc,
// taps 0..8), CS reduce order, heads sum order, and all NMS arithmetic
// bitwise-identical to prior passing versions.
// (Round 12 resubmit: R12 bench was an infra failure, not kernel.)
// ---------------------------------------------------------------------------

#define NPIX 2500      // 50*50
#define NANCH 22500    // 2500*9
#define NKEY 22528     // NANCH padded to 88*256 (sentinel tail)
#define PRE 6000
#define MASKW 94       // ceil(6000/64) usable words
#define MW 96          // storage stride in words
#define JCHUNK 1536    // j-chunk per mask y-block (24 words)
#define CS 8           // cin splits for conv3x3
#define KSLOT 8        // static kept-row load slots per word in scan
#define PW 52          // padded width
#define PSL 2704       // 52*52 padded slice

// ------ fused prep: blocks 0..511 zero-pad x; blocks 512..1087 transpose w -
// wtV[((cin*64 + ocg)*9 + t)*8 + j] = wt[ocg*8+j][cin*9+t]
__global__ __launch_bounds__(256) void prepK(
    const float* __restrict__ x,    // batch-7 base (512,50,50)
    const float* __restrict__ wt,   // (512, 4608)
    float* __restrict__ xpad,       // (512, 52, 52)
    float* __restrict__ wtV)        // (512, 64, 9, 8)
{
    __shared__ float T[64][65];
    const int bx = blockIdx.x;
    if (bx < 512) {
        const int cin = bx;
        const float* src = x + (size_t)cin * NPIX;
        float* dst = xpad + (size_t)cin * PSL;
        for (int i = threadIdx.x; i < PSL; i += 256) {
            const int pr = i / PW;
            const int pc = i - pr * PW;
            float v = 0.f;
            if (pr >= 1 && pr <= 50 && pc >= 1 && pc <= 50)
                v = src[(pr - 1) * 50 + (pc - 1)];
            dst[i] = v;
        }
        return;
    }
    const int idx  = bx - 512;           // 0..575 = 72 x 8
    const int ct0  = (idx % 72) * 64;
    const int ocb  = (idx / 72) * 64;
    const int tid  = threadIdx.x;
    const int cidx = tid & 63;
    const int r4   = tid >> 6;
    #pragma unroll
    for (int i = 0; i < 16; ++i) {
        const int o = r4 + i * 4;
        T[o][cidx] = wt[(size_t)(ocb + o) * 4608 + ct0 + cidx];
    }
    __syncthreads();
    #pragma unroll
    for (int i = 0; i < 16; ++i) {
        const int ctl = ct0 + r4 + i * 4;
        const int cin = ctl / 9;
        const int t   = ctl - cin * 9;
        const int oc  = ocb + cidx;
        wtV[(((size_t)cin * 64 + (oc >> 3)) * 9 + t) * 8 + (oc & 7)] =
            T[cidx][r4 + i * 4];
    }
}

// ------- conv 3x3 v12: adjacent px pair, 3x4 window, 6 float2 loads/cin ----
// grid (64 ocGroups, 5 pairOcts, 8 cin groups) x 256 thr = 10240 waves.
// Thread owns px pair (2q, 2q+1), q = pb*64+lane (pairs never cross a row:
// 50 cols = 25 pairs/row, col start even). Shared window = rows r..r+2 x
// cols c..c+3 (padded coords) = 6 naturally-aligned float2 loads with
// immediate offsets off ONE pointer (+PSL/cin). 144 FMA share 72 SGPR
// weights. Per-accumulator FMA order bitwise-identical (cin asc, taps 0..8).
__global__ __launch_bounds__(256) void conv3x3_v12(
    const float* __restrict__ xpad, // padded batch-7 (512,52,52)
    const float* __restrict__ wtV,  // (512, 64, 9, 8)
    float* __restrict__ part2)      // (CS, 512, 2500)
{
    const int tid  = threadIdx.x;
    const int lane = tid & 63;
    const int wv   = tid >> 6;
    const int ocg  = blockIdx.x;            // 0..63 -> oc = ocg*8 + j
    const int pb   = blockIdx.y * 4 + wv;   // 0..19
    const int cing = blockIdx.z * 64;
    const int pq   = pb * 64 + lane;        // pair index 0..1279
    const bool act = (pq < 1250);
    const int pqc  = act ? pq : 0;
    const int r    = pqc / 25;              // image row 0..49
    const int c    = (pqc - r * 25) * 2;    // even image col 0..48

    // window top-left (padded coords): rows r..r+2, cols c..c+3; all <= 51.
    // image px0=(r,c): center padded (r+1,c+1); taps = cols c..c+2 (padded).
    const float* xb = xpad + (size_t)cing * PSL + r * PW + c;

    float acc0[8], acc1[8];
    #pragma unroll
    for (int j = 0; j < 8; ++j) { acc0[j] = 0.f; acc1[j] = 0.f; }

    const float* wbase = wtV + ((size_t)cing * 64 + ocg) * 72;

    for (int cin = 0; cin < 64; ++cin) {
        const float* xr = xb + (size_t)cin * PSL;
        const float2 w00 = *(const float2*)(xr);
        const float2 w01 = *(const float2*)(xr + 2);
        const float2 w10 = *(const float2*)(xr + PW);
        const float2 w11 = *(const float2*)(xr + PW + 2);
        const float2 w20 = *(const float2*)(xr + 2 * PW);
        const float2 w21 = *(const float2*)(xr + 2 * PW + 2);

        const float* wp = wbase + (size_t)cin * 4608;   // 64*72
        #pragma unroll
        for (int j = 0; j < 8; ++j) {
            float a = acc0[j], b = acc1[j];
            const float t0 = wp[0 * 8 + j]; a = fmaf(t0, w00.x, a); b = fmaf(t0, w00.y, b);
            const float t1 = wp[1 * 8 + j]; a = fmaf(t1, w00.y, a); b = fmaf(t1, w01.x, b);
            const float t2 = wp[2 * 8 + j]; a = fmaf(t2, w01.x, a); b = fmaf(t2, w01.y, b);
            const float t3 = wp[3 * 8 + j]; a = fmaf(t3, w10.x, a); b = fmaf(t3, w10.y, b);
            const float t4 = wp[4 * 8 + j]; a = fmaf(t4, w10.y, a); b = fmaf(t4, w11.x, b);
            const float t5 = wp[5 * 8 + j]; a = fmaf(t5, w11.x, a); b = fmaf(t5, w11.y, b);
            const float t6 = wp[6 * 8 + j]; a = fmaf(t6, w20.x, a); b = fmaf(t6, w20.y, b);
            const float t7 = wp[7 * 8 + j]; a = fmaf(t7, w20.y, a); b = fmaf(t7, w21.x, b);
            const float t8 = wp[8 * 8 + j]; a = fmaf(t8, w21.x, a); b = fmaf(t8, w21.y, b);
            acc0[j] = a; acc1[j] = b;
        }
    }

    if (act) {   // coalesced float2 stores (offset even: 2500 even, 2pq even)
        float* dst = part2 + ((size_t)blockIdx.z * 512 + ocg * 8) * NPIX + 2 * pq;
        #pragma unroll
        for (int j = 0; j < 8; ++j)
            *(float2*)(dst + (size_t)j * NPIX) = make_float2(acc0[j], acc1[j]);
    }
}

// ------------ reduce partials + bias + leaky (float4 vectorized) -----------
__global__ __launch_bounds__(256) void reduce_leaky4(
    const float* __restrict__ part2, const float* __restrict__ bias,
    float* __restrict__ feat)
{
    const int oc = blockIdx.x;
    const float b = bias[oc];
    float4* dstv = (float4*)(feat + (size_t)oc * NPIX);
    for (int q = threadIdx.x; q < 625; q += 256) {
        float4 s = make_float4(0.f, 0.f, 0.f, 0.f);
        #pragma unroll
        for (int k = 0; k < CS; ++k) {
            const float4 v = *(const float4*)(part2 + ((size_t)k * 512 + oc) * NPIX + q * 4);
            s.x += v.x; s.y += v.y; s.z += v.z; s.w += v.w;
        }
        s.x += b; s.y += b; s.z += b; s.w += b;
        s.x = (s.x >= 0.f) ? s.x : 0.01f * s.x;
        s.y = (s.y >= 0.f) ? s.y : 0.01f * s.y;
        s.z = (s.z >= 0.f) ? s.z : 0.01f * s.z;
        s.w = (s.w >= 0.f) ? s.w : 0.01f * s.w;
        dstv[q] = s;
    }
}

// -------- 1x1 heads: 4-wave cin split + LDS tree reduce, k-split x3 --------
__global__ __launch_bounds__(256) void conv1x1_heads(
    const float* __restrict__ feat,
    const float* __restrict__ rw, const float* __restrict__ rb,
    const float* __restrict__ cw, const float* __restrict__ cb,
    float* __restrict__ regcls)   // (54, 2500)
{
    __shared__ float sAcc[3][6][64];
    const int tid  = threadIdx.x;
    const int lane = tid & 63;
    const int wv   = tid >> 6;
    const int pix0 = blockIdx.x * 64 + lane;
    const bool act = (pix0 < NPIX);
    const int pix  = act ? pix0 : (NPIX - 1);
    const int chunk = blockIdx.y;
    const int k0    = blockIdx.z * 6;            // 0, 6, 12
    const float* wb; const float* bb; int ocbase;
    if (chunk == 0)      { wb = rw;            bb = rb;      ocbase = 0;  }
    else if (chunk == 1) { wb = rw + 18 * 512; bb = rb + 18; ocbase = 18; }
    else                 { wb = cw;            bb = cb;      ocbase = 36; }

    float acc[6];
    #pragma unroll
    for (int k = 0; k < 6; ++k) acc[k] = 0.f;

    const int c0 = wv * 128;
    for (int cin = c0; cin < c0 + 128; ++cin) {
        const float v = feat[(size_t)cin * NPIX + pix];
        #pragma unroll
        for (int k = 0; k < 6; ++k)
            acc[k] = fmaf(wb[(k0 + k) * 512 + cin], v, acc[k]);
    }
    if (wv > 0) {
        #pragma unroll
        for (int k = 0; k < 6; ++k) sAcc[wv - 1][k][lane] = acc[k];
    }
    __syncthreads();
    if (wv == 0 && act) {
        #pragma unroll
        for (int k = 0; k < 6; ++k) {
            float s = acc[k];
            s += sAcc[0][k][lane];
            s += sAcc[1][k][lane];
            s += sAcc[2][k][lane];
            regcls[(size_t)(ocbase + k0 + k) * NPIX + pix] = s + bb[k0 + k];
        }
    }
}

// ------- decode: anchors, softmax score, sortable key (+ rank zeroing) -----
__global__ __launch_bounds__(256) void decodeK(
    const float* __restrict__ regcls,
    float4* __restrict__ boxes,
    unsigned long long* __restrict__ keys,
    int* __restrict__ rank)
{
    const int i = blockIdx.x * 256 + threadIdx.x;
    if (i < NANCH) rank[i] = 0;               // replaces hipMemsetAsync
    if (i >= NANCH) {
        if (i < NKEY) keys[i] = 0xFFFFFFFFFFFFFFFFull;  // sentinel: > all keys
        return;
    }
    const int pos = i / 9;
    const int a   = i - pos * 9;
    const int hh  = pos / 50;
    const int wwp = pos - hh * 50;
    const int r = a / 3, s = a - r * 3;

    const float base_s[3] = {128.f, 256.f, 512.f};
    const float sq [3] = {0.70710678118654752440f, 1.0f, 1.41421356237309504880f};
    const float sqi[3] = {1.41421356237309504880f, 1.0f, 0.70710678118654752440f};
    const float hs = base_s[s] * sq[r];
    const float ws = base_s[s] * sqi[r];
    const float cx = (float)(hh * 16 + 8);    // cx indexed by h (reference quirk)
    const float cy = (float)(wwp * 16 + 8);
    const float ax = cx - ws * 0.5f;
    const float ay = cy - hs * 0.5f;

    const float pr0 = regcls[(size_t)(a * 4 + 0) * NPIX + pos];
    const float pr1 = regcls[(size_t)(a * 4 + 1) * NPIX + pos];
    const float pr2 = regcls[(size_t)(a * 4 + 2) * NPIX + pos];
    const float pr3 = regcls[(size_t)(a * 4 + 3) * NPIX + pos];
    const float c0  = regcls[(size_t)(36 + a * 2 + 0) * NPIX + pos];
    const float c1  = regcls[(size_t)(36 + a * 2 + 1) * NPIX + pos];

    const float m  = fmaxf(c0, c1);
    const float e0 = expf(c0 - m);
    const float e1 = expf(c1 - m);
    const float score = e1 / (e0 + e1);

    const float t0 = pr0 + ax;
    const float t1 = pr1 + ay;
    const float hi = 799.0f;
    const float rx1 = fminf(fmaxf(t0, 0.f), hi);
    const float ry1 = fminf(fmaxf(t1, 0.f), hi);
    const float rx2 = fminf(fmaxf((t0 + pr2) + ws, 0.f), hi);
    const float ry2 = fminf(fmaxf((t1 + pr3) + hs, 0.f), hi);
    const float bw = pr2 + ws;
    const float bh = pr3 + hs;
    const bool valid = (bw >= 16.f) && (bh >= 16.f);
    const float sc = valid ? score : -__builtin_inff();

    unsigned u = __float_as_uint(sc);
    u = (u & 0x80000000u) ? ~u : (u | 0x80000000u);  // monotone ascending map
    const unsigned k32 = ~u;                          // descending score
    keys[i]  = ((unsigned long long)k32 << 32) | (unsigned)i;  // tie: asc index
    boxes[i] = make_float4(rx1, ry1, rx2, ry2);
}

// ---------------- O(N^2) rank (stable argsort position) --------------------
__global__ __launch_bounds__(256) void rankK(
    const unsigned long long* __restrict__ keys, int* __restrict__ rank)
{
    const int i = blockIdx.x * 256 + threadIdx.x;
    const unsigned long long my = (i < NANCH) ? keys[i] : 0ull;
    const unsigned long long* kj = keys + blockIdx.y * 2816;
    int cnt = 0;
    for (int t = 0; t < 2816; t += 8) {
        #pragma unroll
        for (int q = 0; q < 8; ++q)
            cnt += (kj[t + q] < my) ? 1 : 0;
    }
    if (i < NANCH) atomicAdd(&rank[i], cnt);
}

__global__ __launch_bounds__(256) void scatterK(
    const float4* __restrict__ boxes, const int* __restrict__ rank,
    float4* __restrict__ sboxes)
{
    const int i = blockIdx.x * 256 + threadIdx.x;
    if (i < NANCH) {
        const int r = rank[i];
        if (r < PRE) sboxes[r] = boxes[i];
    }
}

// ------------- NMS suppression bitmask v2: lane = j, ballot, NO LDS --------
__global__ __launch_bounds__(256) void nmsMaskK(
    const float4* __restrict__ sb, unsigned long long* __restrict__ mask)
{
    const int tid  = threadIdx.x;
    const int lane = tid & 63;
    const int wv   = tid >> 6;
    const int i0   = blockIdx.x * 16 + wv * 4;   // 4 i-rows per wave
    const int jbase = blockIdx.y * JCHUNK;

    float ix1[4], iy1[4], ix2[4], iy2[4], iar[4];
    #pragma unroll
    for (int ii = 0; ii < 4; ++ii) {
        const float4 b = sb[i0 + ii];
        ix1[ii] = b.x; iy1[ii] = b.y; ix2[ii] = b.z; iy2[ii] = b.w;
        iar[ii] = (b.z - b.x + 1.f) * (b.w - b.y + 1.f);
    }

    for (int w = 0; w < 24; ++w) {
        const int j  = jbase + w * 64 + lane;
        const int jc = (j < PRE) ? j : 0;            // clamp OOB load
        const float4 bj = sb[jc];
        const float jar = (bj.z - bj.x + 1.f) * (bj.w - bj.y + 1.f);
        #pragma unroll
        for (int ii = 0; ii < 4; ++ii) {
            const int i = i0 + ii;
            const float xx1 = fmaxf(ix1[ii], bj.x);
            const float yy1 = fmaxf(iy1[ii], bj.y);
            const float xx2 = fminf(ix2[ii], bj.z);
            const float yy2 = fmaxf(iy2[ii], bj.w);   // reference bug: max
            const float wvv = fmaxf(0.f, xx2 - xx1 + 1.f);
            const float hvv = fmaxf(0.f, yy2 - yy1 + 1.f);
            const float inter = wvv * hvv;
            const float ov = inter / ((iar[ii] + jar) - inter);  // precise div
            const bool pred = (j > i) && (j < PRE) && (ov > 0.7f);
            const unsigned long long bits = __ballot(pred);
            if (lane == 0)
                mask[(size_t)i * MW + blockIdx.y * 24 + w] = bits;
        }
    }
}

// ------------- PAIRED word-serial NMS scan + output (single wave) ----------
__global__ __launch_bounds__(64) void nmsScanOutK(
    const unsigned long long* __restrict__ mask,
    const float4* __restrict__ sb,
    float* __restrict__ out)
{
    __shared__ int sKept[300];
    __shared__ unsigned long long sKeepW[MASKW];
    const int lane = threadIdx.x;

    unsigned long long rem0 = 0ull, rem1 = 0ull;   // lane l: words l, 64+l
    int cnt = 0;
    int done = 0;

    // preload pair 0 diagonals
    unsigned long long d00 = mask[(size_t)lane * MW + 0];
    unsigned long long d01 = mask[(size_t)lane * MW + 1];
    unsigned long long d11 = mask[(size_t)(64 + lane) * MW + 1];

    for (int p = 0; p < 47 && !done; ++p) {
        const int g0 = 2 * p, g1 = 2 * p + 1;

        // prefetch next pair's three diagonal words (overlap with this round)
        unsigned long long n00 = 0ull, n01 = 0ull, n11 = 0ull;
        if (p + 1 < 47) {
            const int h0 = g0 + 2, h1 = g0 + 3;
            const int ra = h0 * 64 + lane;
            const int rb = h1 * 64 + lane;
            n00 = mask[(size_t)ra * MW + h0];
            n01 = mask[(size_t)ra * MW + h1];
            if (rb < PRE) n11 = mask[(size_t)rb * MW + h1];
        }

        // broadcast current suppression words g0, g1 from rem
        unsigned long long cur0, cur1;
        {
            unsigned lo, hi;
            if (g0 < 64) {
                lo = __builtin_amdgcn_readlane((unsigned)rem0, g0);
                hi = __builtin_amdgcn_readlane((unsigned)(rem0 >> 32), g0);
            } else {
                lo = __builtin_amdgcn_readlane((unsigned)rem1, g0 - 64);
                hi = __builtin_amdgcn_readlane((unsigned)(rem1 >> 32), g0 - 64);
            }
            cur0 = ((unsigned long long)hi << 32) | lo;
            if (g1 < 64) {
                lo = __builtin_amdgcn_readlane((unsigned)rem0, g1);
                hi = __builtin_amdgcn_readlane((unsigned)(rem0 >> 32), g1);
            } else {
                lo = __builtin_amdgcn_readlane((unsigned)rem1, g1 - 64);
                hi = __builtin_amdgcn_readlane((unsigned)(rem1 >> 32), g1 - 64);
            }
            cur1 = ((unsigned long long)hi << 32) | lo;
        }
        const unsigned long long valid0 = ~0ull;    // g0 <= 92: always full
        const unsigned long long valid1 =
            (g1 == MASKW - 1) ? 0x0000FFFFFFFFFFFFull : ~0ull;  // 48 tail bits

        // ---- phase A: drain block g0 keeps (pure ALU) ----
        unsigned long long kb0 = 0ull, kb1 = 0ull;
        for (;;) {
            const unsigned long long nd = (~cur0) & valid0;
            if (!nd) break;
            const int b = __builtin_ctzll(nd);
            if (lane == 0 && cnt < 300) sKept[cnt] = g0 * 64 + b;
            ++cnt;
            kb0 |= (1ull << b);
            if (cnt >= 300) { done = 1; break; }
            const unsigned al = __builtin_amdgcn_readlane((unsigned)d00, b);
            const unsigned ah = __builtin_amdgcn_readlane((unsigned)(d00 >> 32), b);
            const unsigned bl = __builtin_amdgcn_readlane((unsigned)d01, b);
            const unsigned bh = __builtin_amdgcn_readlane((unsigned)(d01 >> 32), b);
            cur0 |= (1ull << b) | (((unsigned long long)ah << 32) | al);
            cur1 |= (((unsigned long long)bh << 32) | bl);
        }
        // ---- phase B: drain block g1 keeps ----
        if (!done) {
            for (;;) {
                const unsigned long long nd = (~cur1) & valid1;
                if (!nd) break;
                const int b = __builtin_ctzll(nd);
                if (lane == 0 && cnt < 300) sKept[cnt] = g1 * 64 + b;
                ++cnt;
                kb1 |= (1ull << b);
                if (cnt >= 300) { done = 1; break; }
                const unsigned cl = __builtin_amdgcn_readlane((unsigned)d11, b);
                const unsigned ch = __builtin_amdgcn_readlane((unsigned)(d11 >> 32), b);
                cur1 |= (1ull << b) | (((unsigned long long)ch << 32) | cl);
            }
        }
        if (lane == 0) { sKeepW[g0] = kb0; sKeepW[g1] = kb1; }

        // ---- batched kept-row loads for BOTH blocks, one rem update ----
        if (!done && (kb0 | kb1)) {
            unsigned long long a0 = 0ull, a1 = 0ull;
            {
                int kbit[KSLOT];
                unsigned long long t = kb0;
                #pragma unroll
                for (int s = 0; s < KSLOT; ++s) {
                    kbit[s] = t ? __builtin_ctzll(t) : 64;
                    t &= t - 1;
                }
                #pragma unroll
                for (int s = 0; s < KSLOT; ++s) {
                    if (kbit[s] < 64) {            // wave-uniform branch
                        const unsigned long long* pr =
                            mask + (size_t)(g0 * 64 + kbit[s]) * MW;
                        a0 |= pr[lane];
                        a1 |= (lane < MASKW - 64) ? pr[64 + lane] : 0ull;
                    }
                }
                while (t) {                         // >KSLOT overflow (rare)
                    const int b = __builtin_ctzll(t); t &= t - 1;
                    const unsigned long long* pr =
                        mask + (size_t)(g0 * 64 + b) * MW;
                    a0 |= pr[lane];
                    a1 |= (lane < MASKW - 64) ? pr[64 + lane] : 0ull;
                }
            }
            {
                int kbit[KSLOT];
                unsigned long long t = kb1;
                #pragma unroll
                for (int s = 0; s < KSLOT; ++s) {
                    kbit[s] = t ? __builtin_ctzll(t) : 64;
                    t &= t - 1;
                }
                #pragma unroll
                for (int s = 0; s < KSLOT; ++s) {
                    if (kbit[s] < 64) {            // wave-uniform branch
                        const unsigned long long* pr =
                            mask + (size_t)(g1 * 64 + kbit[s]) * MW;
                        a0 |= pr[lane];
                        a1 |= (lane < MASKW - 64) ? pr[64 + lane] : 0ull;
                    }
                }
                while (t) {                         // >KSLOT overflow (rare)
                    const int b = __builtin_ctzll(t); t &= t - 1;
                    const unsigned long long* pr =
                        mask + (size_t)(g1 * 64 + b) * MW;
                    a0 |= pr[lane];
                    a1 |= (lane < MASKW - 64) ? pr[64 + lane] : 0ull;
                }
            }
            rem0 |= a0;
            rem1 |= a1;
        }
        d00 = n00; d01 = n01; d11 = n11;
    }

    __syncthreads();

    if (cnt < 300) {                                 // filler: unkept, asc index
        int c = cnt;
        for (int g = 0; g < MASKW && c < 300; ++g) {
            const unsigned long long valid =
                (g == MASKW - 1) ? 0x0000FFFFFFFFFFFFull : ~0ull;
            unsigned long long u = (~sKeepW[g]) & valid;
            while (u && c < 300) {
                const int b = __builtin_ctzll(u); u &= u - 1;
                if (lane == 0) sKept[c] = g * 64 + b;
                ++c;
            }
        }
    }
    __syncthreads();

    for (int s = lane; s < 300; s += 64) {
        const float4 b = sb[sKept[s]];
        out[s * 4 + 0] = b.x;
        out[s * 4 + 1] = b.y;
        out[s * 4 + 2] = b.z - b.x + 1.0f;
        out[s * 4 + 3] = b.w - b.y + 1.0f;
    }
}

// ---------------------------------------------------------------------------
extern "C" void kernel_launch(void* const* d_in, const int* in_sizes, int n_in,
                              void* d_out, int out_size, void* d_ws, size_t ws_size,
                              hipStream_t stream)
{
    (void)in_sizes; (void)n_in; (void)out_size; (void)ws_size;
    const float* x   = (const float*)d_in[0] + (size_t)7 * 512 * NPIX; // batch 7
    const float* cw3 = (const float*)d_in[1];
    const float* cb3 = (const float*)d_in[2];
    const float* rw  = (const float*)d_in[3];
    const float* rb  = (const float*)d_in[4];
    const float* clw = (const float*)d_in[5];
    const float* clb = (const float*)d_in[6];
    float* out = (float*)d_out;

    char* p = (char*)d_ws;
    auto alloc = [&](size_t n) { char* r = p; p += (n + 255) & ~(size_t)255; return r; };
    float*  part2  = (float*)alloc((size_t)CS * 512 * NPIX * 4);  // 41 MB
    float*  wtV    = (float*)alloc((size_t)4608 * 512 * 4);       // 9.4 MB
    float*  xpad   = (float*)alloc((size_t)512 * PSL * 4);        // 5.5 MB
    float*  feat   = (float*)alloc((size_t)512 * NPIX * 4);       // 5.12 MB
    float*  regcls = (float*)alloc((size_t)54 * NPIX * 4);        // 0.54 MB
    float4* boxes  = (float4*)alloc((size_t)NANCH * 16);          // 0.36 MB
    unsigned long long* keys = (unsigned long long*)alloc((size_t)NKEY * 8);
    int*    rank   = (int*)alloc((size_t)NANCH * 4);
    float4* sboxes = (float4*)alloc((size_t)PRE * 16);
    unsigned long long* mask = (unsigned long long*)alloc((size_t)PRE * MW * 8); // 4.6 MB

    prepK         <<<1088, 256, 0, stream>>>(x, cw3, xpad, wtV);
    conv3x3_v12   <<<dim3(64, 5, CS), 256, 0, stream>>>(xpad, wtV, part2);
    reduce_leaky4 <<<512, 256, 0, stream>>>(part2, cb3, feat);
    conv1x1_heads <<<dim3(40, 3, 3), 256, 0, stream>>>(feat, rw, rb, clw, clb, regcls);
    decodeK       <<<88, 256, 0, stream>>>(regcls, boxes, keys, rank);
    rankK         <<<dim3(88, 8), 256, 0, stream>>>(keys, rank);
    scatterK      <<<88, 256, 0, stream>>>(boxes, rank, sboxes);
    nmsMaskK      <<<dim3(375, 4), 256, 0, stream>>>(sboxes, mask);
    nmsScanOutK   <<<1, 64, 0, stream>>>(mask, sboxes, out);
}

// Round 14
// 485.122 us; speedup vs baseline: 1.0410x; 1.0410x over previous
//
#include <hip/hip_runtime.h>

// ---------------------------------------------------------------------------
// RPN forward, MI355X. Only batch element 7 contributes to the output.
// prepK (fused: zero-pad input 512x52x52 + weight->SGPR-layout transpose) ->
// conv3x3 v13 (v9 dataflow, 3 px/thread, EXACT-RESIDENCY grid: 2048 WGs =
// 8 WGs/CU = 32 waves/CU in ONE round; 72 SGPR weights / 216 FMA per cin,
// JIT immediate-offset loads, NO LDS) -> reduce_leaky4 -> 1x1 heads
// (k-split x3) -> decode/score/key (+rank zeroing) -> O(N^2) rank sort ->
// top-6000 -> NMS bitmask v2 (lane=j, ballot, NO LDS; reference's yy2=max
// bug replicated token-identically) -> PAIRED word-serial scan -> 300x4
// boxes. Deterministic fp32: per-accumulator FMA chain (cin asc, taps 0..8),
// CS reduce order, heads sum order, and all NMS arithmetic bitwise-identical
// to prior passing versions.
// ---------------------------------------------------------------------------

#define NPIX 2500      // 50*50
#define NANCH 22500    // 2500*9
#define NKEY 22528     // NANCH padded to 88*256 (sentinel tail)
#define PRE 6000
#define MASKW 94       // ceil(6000/64) usable words
#define MW 96          // storage stride in words
#define JCHUNK 1536    // j-chunk per mask y-block (24 words)
#define CS 8           // cin splits for conv3x3
#define KSLOT 8        // static kept-row load slots per word in scan
#define PW 52          // padded width
#define PSL 2704       // 52*52 padded slice

// ------ fused prep: blocks 0..511 zero-pad x; blocks 512..1087 transpose w -
// wtV[((cin*64 + ocg)*9 + t)*8 + j] = wt[ocg*8+j][cin*9+t]
__global__ __launch_bounds__(256) void prepK(
    const float* __restrict__ x,    // batch-7 base (512,50,50)
    const float* __restrict__ wt,   // (512, 4608)
    float* __restrict__ xpad,       // (512, 52, 52)
    float* __restrict__ wtV)        // (512, 64, 9, 8)
{
    __shared__ float T[64][65];
    const int bx = blockIdx.x;
    if (bx < 512) {
        const int cin = bx;
        const float* src = x + (size_t)cin * NPIX;
        float* dst = xpad + (size_t)cin * PSL;
        for (int i = threadIdx.x; i < PSL; i += 256) {
            const int pr = i / PW;
            const int pc = i - pr * PW;
            float v = 0.f;
            if (pr >= 1 && pr <= 50 && pc >= 1 && pc <= 50)
                v = src[(pr - 1) * 50 + (pc - 1)];
            dst[i] = v;
        }
        return;
    }
    const int idx  = bx - 512;           // 0..575 = 72 x 8
    const int ct0  = (idx % 72) * 64;
    const int ocb  = (idx / 72) * 64;
    const int tid  = threadIdx.x;
    const int cidx = tid & 63;
    const int r4   = tid >> 6;
    #pragma unroll
    for (int i = 0; i < 16; ++i) {
        const int o = r4 + i * 4;
        T[o][cidx] = wt[(size_t)(ocb + o) * 4608 + ct0 + cidx];
    }
    __syncthreads();
    #pragma unroll
    for (int i = 0; i < 16; ++i) {
        const int ctl = ct0 + r4 + i * 4;
        const int cin = ctl / 9;
        const int t   = ctl - cin * 9;
        const int oc  = ocb + cidx;
        wtV[(((size_t)cin * 64 + (oc >> 3)) * 9 + t) * 8 + (oc & 7)] =
            T[cidx][r4 + i * 4];
    }
}

// ---- conv 3x3 v13: 3 px/thread, exact-residency grid, padded, no LDS ------
// grid (64 ocGroups, 4 pxQuads, 8 cin groups) x 256 thr = 2048 WGs =
// 8 WGs/CU = 32 waves/CU: the whole kernel is ONE fully-resident round
// (v9's 10-WG/CU grid ran 2 rounds, the 2nd at 25% residency -> 37% loss).
// Per cin: 27 JIT loads at immediate tap offsets + 216 FMA sharing ONE
// batch of 72 SGPR weights. Per-accumulator FMA order bitwise-identical
// (cin asc, taps 0..8); px partition does not affect any chain.
__global__ __launch_bounds__(256) void conv3x3_v13(
    const float* __restrict__ xpad, // padded batch-7 (512,52,52)
    const float* __restrict__ wtV,  // (512, 64, 9, 8)
    float* __restrict__ part2)      // (CS, 512, 2500)
{
    const int tid  = threadIdx.x;
    const int lane = tid & 63;
    const int wv   = tid >> 6;
    const int ocg  = blockIdx.x;            // 0..63 -> oc = ocg*8 + j
    const int wid  = blockIdx.y * 4 + wv;   // 0..15
    const int cing = blockIdx.z * 64;
    const int base = wid * 64 + lane;       // 0..1023
    const int px0  = base;                  // 0..1023   (always valid)
    const int px1  = base + 1024;           // 1024..2047 (always valid)
    const int px2  = base + 2048;           // 2048..3071
    const bool act2 = (px2 < NPIX);
    const int r0 = px0 / 50, c0 = px0 - r0 * 50;
    const int r1 = px1 / 50, c1 = px1 - r1 * 50;
    const int px2c = act2 ? px2 : 0;
    const int r2 = px2c / 50, c2 = px2c - r2 * 50;

    const float* xb0 = xpad + (size_t)cing * PSL + (r0 + 1) * PW + (c0 + 1);
    const float* xb1 = xpad + (size_t)cing * PSL + (r1 + 1) * PW + (c1 + 1);
    const float* xb2 = xpad + (size_t)cing * PSL + (r2 + 1) * PW + (c2 + 1);

    float acc0[8], acc1[8], acc2[8];
    #pragma unroll
    for (int j = 0; j < 8; ++j) { acc0[j] = 0.f; acc1[j] = 0.f; acc2[j] = 0.f; }

    const float* wbase = wtV + ((size_t)cing * 64 + ocg) * 72;

    for (int cin = 0; cin < 64; ++cin) {
        float v0[9], v1[9], v2[9];
        const float* xa = xb0 + (size_t)cin * PSL;
        const float* xc = xb1 + (size_t)cin * PSL;
        const float* xd = xb2 + (size_t)cin * PSL;
        #pragma unroll
        for (int t = 0; t < 9; ++t) {
            const int dr = t / 3 - 1, dc = t % 3 - 1;
            v0[t] = xa[dr * PW + dc];
            v1[t] = xc[dr * PW + dc];
            v2[t] = xd[dr * PW + dc];
        }
        const float* wp = wbase + (size_t)cin * 4608;   // 64*72
        #pragma unroll
        for (int j = 0; j < 8; ++j) {
            float a = acc0[j];
            float b = acc1[j];
            float c = acc2[j];
            #pragma unroll
            for (int t = 0; t < 9; ++t) {
                const float w = wp[t * 8 + j];
                a = fmaf(w, v0[t], a);
                b = fmaf(w, v1[t], b);
                c = fmaf(w, v2[t], c);
            }
            acc0[j] = a;
            acc1[j] = b;
            acc2[j] = c;
        }
    }

    float* dst = part2 + ((size_t)blockIdx.z * 512 + ocg * 8) * NPIX;
    #pragma unroll
    for (int j = 0; j < 8; ++j) {
        dst[(size_t)j * NPIX + px0] = acc0[j];
        dst[(size_t)j * NPIX + px1] = acc1[j];
    }
    if (act2) {
        #pragma unroll
        for (int j = 0; j < 8; ++j)
            dst[(size_t)j * NPIX + px2] = acc2[j];
    }
}

// ------------ reduce partials + bias + leaky (float4 vectorized) -----------
__global__ __launch_bounds__(256) void reduce_leaky4(
    const float* __restrict__ part2, const float* __restrict__ bias,
    float* __restrict__ feat)
{
    const int oc = blockIdx.x;
    const float b = bias[oc];
    float4* dstv = (float4*)(feat + (size_t)oc * NPIX);
    for (int q = threadIdx.x; q < 625; q += 256) {
        float4 s = make_float4(0.f, 0.f, 0.f, 0.f);
        #pragma unroll
        for (int k = 0; k < CS; ++k) {
            const float4 v = *(const float4*)(part2 + ((size_t)k * 512 + oc) * NPIX + q * 4);
            s.x += v.x; s.y += v.y; s.z += v.z; s.w += v.w;
        }
        s.x += b; s.y += b; s.z += b; s.w += b;
        s.x = (s.x >= 0.f) ? s.x : 0.01f * s.x;
        s.y = (s.y >= 0.f) ? s.y : 0.01f * s.y;
        s.z = (s.z >= 0.f) ? s.z : 0.01f * s.z;
        s.w = (s.w >= 0.f) ? s.w : 0.01f * s.w;
        dstv[q] = s;
    }
}

// -------- 1x1 heads: 4-wave cin split + LDS tree reduce, k-split x3 --------
__global__ __launch_bounds__(256) void conv1x1_heads(
    const float* __restrict__ feat,
    const float* __restrict__ rw, const float* __restrict__ rb,
    const float* __restrict__ cw, const float* __restrict__ cb,
    float* __restrict__ regcls)   // (54, 2500)
{
    __shared__ float sAcc[3][6][64];
    const int tid  = threadIdx.x;
    const int lane = tid & 63;
    const int wv   = tid >> 6;
    const int pix0 = blockIdx.x * 64 + lane;
    const bool act = (pix0 < NPIX);
    const int pix  = act ? pix0 : (NPIX - 1);
    const int chunk = blockIdx.y;
    const int k0    = blockIdx.z * 6;            // 0, 6, 12
    const float* wb; const float* bb; int ocbase;
    if (chunk == 0)      { wb = rw;            bb = rb;      ocbase = 0;  }
    else if (chunk == 1) { wb = rw + 18 * 512; bb = rb + 18; ocbase = 18; }
    else                 { wb = cw;            bb = cb;      ocbase = 36; }

    float acc[6];
    #pragma unroll
    for (int k = 0; k < 6; ++k) acc[k] = 0.f;

    const int c0 = wv * 128;
    for (int cin = c0; cin < c0 + 128; ++cin) {
        const float v = feat[(size_t)cin * NPIX + pix];
        #pragma unroll
        for (int k = 0; k < 6; ++k)
            acc[k] = fmaf(wb[(k0 + k) * 512 + cin], v, acc[k]);
    }
    if (wv > 0) {
        #pragma unroll
        for (int k = 0; k < 6; ++k) sAcc[wv - 1][k][lane] = acc[k];
    }
    __syncthreads();
    if (wv == 0 && act) {
        #pragma unroll
        for (int k = 0; k < 6; ++k) {
            float s = acc[k];
            s += sAcc[0][k][lane];
            s += sAcc[1][k][lane];
            s += sAcc[2][k][lane];
            regcls[(size_t)(ocbase + k0 + k) * NPIX + pix] = s + bb[k0 + k];
        }
    }
}

// ------- decode: anchors, softmax score, sortable key (+ rank zeroing) -----
__global__ __launch_bounds__(256) void decodeK(
    const float* __restrict__ regcls,
    float4* __restrict__ boxes,
    unsigned long long* __restrict__ keys,
    int* __restrict__ rank)
{
    const int i = blockIdx.x * 256 + threadIdx.x;
    if (i < NANCH) rank[i] = 0;               // replaces hipMemsetAsync
    if (i >= NANCH) {
        if (i < NKEY) keys[i] = 0xFFFFFFFFFFFFFFFFull;  // sentinel: > all keys
        return;
    }
    const int pos = i / 9;
    const int a   = i - pos * 9;
    const int hh  = pos / 50;
    const int wwp = pos - hh * 50;
    const int r = a / 3, s = a - r * 3;

    const float base_s[3] = {128.f, 256.f, 512.f};
    const float sq [3] = {0.70710678118654752440f, 1.0f, 1.41421356237309504880f};
    const float sqi[3] = {1.41421356237309504880f, 1.0f, 0.70710678118654752440f};
    const float hs = base_s[s] * sq[r];
    const float ws = base_s[s] * sqi[r];
    const float cx = (float)(hh * 16 + 8);    // cx indexed by h (reference quirk)
    const float cy = (float)(wwp * 16 + 8);
    const float ax = cx - ws * 0.5f;
    const float ay = cy - hs * 0.5f;

    const float pr0 = regcls[(size_t)(a * 4 + 0) * NPIX + pos];
    const float pr1 = regcls[(size_t)(a * 4 + 1) * NPIX + pos];
    const float pr2 = regcls[(size_t)(a * 4 + 2) * NPIX + pos];
    const float pr3 = regcls[(size_t)(a * 4 + 3) * NPIX + pos];
    const float c0  = regcls[(size_t)(36 + a * 2 + 0) * NPIX + pos];
    const float c1  = regcls[(size_t)(36 + a * 2 + 1) * NPIX + pos];

    const float m  = fmaxf(c0, c1);
    const float e0 = expf(c0 - m);
    const float e1 = expf(c1 - m);
    const float score = e1 / (e0 + e1);

    const float t0 = pr0 + ax;
    const float t1 = pr1 + ay;
    const float hi = 799.0f;
    const float rx1 = fminf(fmaxf(t0, 0.f), hi);
    const float ry1 = fminf(fmaxf(t1, 0.f), hi);
    const float rx2 = fminf(fmaxf((t0 + pr2) + ws, 0.f), hi);
    const float ry2 = fminf(fmaxf((t1 + pr3) + hs, 0.f), hi);
    const float bw = pr2 + ws;
    const float bh = pr3 + hs;
    const bool valid = (bw >= 16.f) && (bh >= 16.f);
    const float sc = valid ? score : -__builtin_inff();

    unsigned u = __float_as_uint(sc);
    u = (u & 0x80000000u) ? ~u : (u | 0x80000000u);  // monotone ascending map
    const unsigned k32 = ~u;                          // descending score
    keys[i]  = ((unsigned long long)k32 << 32) | (unsigned)i;  // tie: asc index
    boxes[i] = make_float4(rx1, ry1, rx2, ry2);
}

// ---------------- O(N^2) rank (stable argsort position) --------------------
__global__ __launch_bounds__(256) void rankK(
    const unsigned long long* __restrict__ keys, int* __restrict__ rank)
{
    const int i = blockIdx.x * 256 + threadIdx.x;
    const unsigned long long my = (i < NANCH) ? keys[i] : 0ull;
    const unsigned long long* kj = keys + blockIdx.y * 2816;
    int cnt = 0;
    for (int t = 0; t < 2816; t += 8) {
        #pragma unroll
        for (int q = 0; q < 8; ++q)
            cnt += (kj[t + q] < my) ? 1 : 0;
    }
    if (i < NANCH) atomicAdd(&rank[i], cnt);
}

__global__ __launch_bounds__(256) void scatterK(
    const float4* __restrict__ boxes, const int* __restrict__ rank,
    float4* __restrict__ sboxes)
{
    const int i = blockIdx.x * 256 + threadIdx.x;
    if (i < NANCH) {
        const int r = rank[i];
        if (r < PRE) sboxes[r] = boxes[i];
    }
}

// ------------- NMS suppression bitmask v2: lane = j, ballot, NO LDS --------
__global__ __launch_bounds__(256) void nmsMaskK(
    const float4* __restrict__ sb, unsigned long long* __restrict__ mask)
{
    const int tid  = threadIdx.x;
    const int lane = tid & 63;
    const int wv   = tid >> 6;
    const int i0   = blockIdx.x * 16 + wv * 4;   // 4 i-rows per wave
    const int jbase = blockIdx.y * JCHUNK;

    float ix1[4], iy1[4], ix2[4], iy2[4], iar[4];
    #pragma unroll
    for (int ii = 0; ii < 4; ++ii) {
        const float4 b = sb[i0 + ii];
        ix1[ii] = b.x; iy1[ii] = b.y; ix2[ii] = b.z; iy2[ii] = b.w;
        iar[ii] = (b.z - b.x + 1.f) * (b.w - b.y + 1.f);
    }

    for (int w = 0; w < 24; ++w) {
        const int j  = jbase + w * 64 + lane;
        const int jc = (j < PRE) ? j : 0;            // clamp OOB load
        const float4 bj = sb[jc];
        const float jar = (bj.z - bj.x + 1.f) * (bj.w - bj.y + 1.f);
        #pragma unroll
        for (int ii = 0; ii < 4; ++ii) {
            const int i = i0 + ii;
            const float xx1 = fmaxf(ix1[ii], bj.x);
            const float yy1 = fmaxf(iy1[ii], bj.y);
            const float xx2 = fminf(ix2[ii], bj.z);
            const float yy2 = fmaxf(iy2[ii], bj.w);   // reference bug: max
            const float wvv = fmaxf(0.f, xx2 - xx1 + 1.f);
            const float hvv = fmaxf(0.f, yy2 - yy1 + 1.f);
            const float inter = wvv * hvv;
            const float ov = inter / ((iar[ii] + jar) - inter);  // precise div
            const bool pred = (j > i) && (j < PRE) && (ov > 0.7f);
            const unsigned long long bits = __ballot(pred);
            if (lane == 0)
                mask[(size_t)i * MW + blockIdx.y * 24 + w] = bits;
        }
    }
}

// ------------- PAIRED word-serial NMS scan + output (single wave) ----------
__global__ __launch_bounds__(64) void nmsScanOutK(
    const unsigned long long* __restrict__ mask,
    const float4* __restrict__ sb,
    float* __restrict__ out)
{
    __shared__ int sKept[300];
    __shared__ unsigned long long sKeepW[MASKW];
    const int lane = threadIdx.x;

    unsigned long long rem0 = 0ull, rem1 = 0ull;   // lane l: words l, 64+l
    int cnt = 0;
    int done = 0;

    // preload pair 0 diagonals
    unsigned long long d00 = mask[(size_t)lane * MW + 0];
    unsigned long long d01 = mask[(size_t)lane * MW + 1];
    unsigned long long d11 = mask[(size_t)(64 + lane) * MW + 1];

    for (int p = 0; p < 47 && !done; ++p) {
        const int g0 = 2 * p, g1 = 2 * p + 1;

        // prefetch next pair's three diagonal words (overlap with this round)
        unsigned long long n00 = 0ull, n01 = 0ull, n11 = 0ull;
        if (p + 1 < 47) {
            const int h0 = g0 + 2, h1 = g0 + 3;
            const int ra = h0 * 64 + lane;
            const int rb = h1 * 64 + lane;
            n00 = mask[(size_t)ra * MW + h0];
            n01 = mask[(size_t)ra * MW + h1];
            if (rb < PRE) n11 = mask[(size_t)rb * MW + h1];
        }

        // broadcast current suppression words g0, g1 from rem
        unsigned long long cur0, cur1;
        {
            unsigned lo, hi;
            if (g0 < 64) {
                lo = __builtin_amdgcn_readlane((unsigned)rem0, g0);
                hi = __builtin_amdgcn_readlane((unsigned)(rem0 >> 32), g0);
            } else {
                lo = __builtin_amdgcn_readlane((unsigned)rem1, g0 - 64);
                hi = __builtin_amdgcn_readlane((unsigned)(rem1 >> 32), g0 - 64);
            }
            cur0 = ((unsigned long long)hi << 32) | lo;
            if (g1 < 64) {
                lo = __builtin_amdgcn_readlane((unsigned)rem0, g1);
                hi = __builtin_amdgcn_readlane((unsigned)(rem0 >> 32), g1);
            } else {
                lo = __builtin_amdgcn_readlane((unsigned)rem1, g1 - 64);
                hi = __builtin_amdgcn_readlane((unsigned)(rem1 >> 32), g1 - 64);
            }
            cur1 = ((unsigned long long)hi << 32) | lo;
        }
        const unsigned long long valid0 = ~0ull;    // g0 <= 92: always full
        const unsigned long long valid1 =
            (g1 == MASKW - 1) ? 0x0000FFFFFFFFFFFFull : ~0ull;  // 48 tail bits

        // ---- phase A: drain block g0 keeps (pure ALU) ----
        unsigned long long kb0 = 0ull, kb1 = 0ull;
        for (;;) {
            const unsigned long long nd = (~cur0) & valid0;
            if (!nd) break;
            const int b = __builtin_ctzll(nd);
            if (lane == 0 && cnt < 300) sKept[cnt] = g0 * 64 + b;
            ++cnt;
            kb0 |= (1ull << b);
            if (cnt >= 300) { done = 1; break; }
            const unsigned al = __builtin_amdgcn_readlane((unsigned)d00, b);
            const unsigned ah = __builtin_amdgcn_readlane((unsigned)(d00 >> 32), b);
            const unsigned bl = __builtin_amdgcn_readlane((unsigned)d01, b);
            const unsigned bh = __builtin_amdgcn_readlane((unsigned)(d01 >> 32), b);
            cur0 |= (1ull << b) | (((unsigned long long)ah << 32) | al);
            cur1 |= (((unsigned long long)bh << 32) | bl);
        }
        // ---- phase B: drain block g1 keeps ----
        if (!done) {
            for (;;) {
                const unsigned long long nd = (~cur1) & valid1;
                if (!nd) break;
                const int b = __builtin_ctzll(nd);
                if (lane == 0 && cnt < 300) sKept[cnt] = g1 * 64 + b;
                ++cnt;
                kb1 |= (1ull << b);
                if (cnt >= 300) { done = 1; break; }
                const unsigned cl = __builtin_amdgcn_readlane((unsigned)d11, b);
                const unsigned ch = __builtin_amdgcn_readlane((unsigned)(d11 >> 32), b);
                cur1 |= (1ull << b) | (((unsigned long long)ch << 32) | cl);
            }
        }
        if (lane == 0) { sKeepW[g0] = kb0; sKeepW[g1] = kb1; }

        // ---- batched kept-row loads for BOTH blocks, one rem update ----
        if (!done && (kb0 | kb1)) {
            unsigned long long a0 = 0ull, a1 = 0ull;
            {
                int kbit[KSLOT];
                unsigned long long t = kb0;
                #pragma unroll
                for (int s = 0; s < KSLOT; ++s) {
                    kbit[s] = t ? __builtin_ctzll(t) : 64;
                    t &= t - 1;
                }
                #pragma unroll
                for (int s = 0; s < KSLOT; ++s) {
                    if (kbit[s] < 64) {            // wave-uniform branch
                        const unsigned long long* pr =
                            mask + (size_t)(g0 * 64 + kbit[s]) * MW;
                        a0 |= pr[lane];
                        a1 |= (lane < MASKW - 64) ? pr[64 + lane] : 0ull;
                    }
                }
                while (t) {                         // >KSLOT overflow (rare)
                    const int b = __builtin_ctzll(t); t &= t - 1;
                    const unsigned long long* pr =
                        mask + (size_t)(g0 * 64 + b) * MW;
                    a0 |= pr[lane];
                    a1 |= (lane < MASKW - 64) ? pr[64 + lane] : 0ull;
                }
            }
            {
                int kbit[KSLOT];
                unsigned long long t = kb1;
                #pragma unroll
                for (int s = 0; s < KSLOT; ++s) {
                    kbit[s] = t ? __builtin_ctzll(t) : 64;
                    t &= t - 1;
                }
                #pragma unroll
                for (int s = 0; s < KSLOT; ++s) {
                    if (kbit[s] < 64) {            // wave-uniform branch
                        const unsigned long long* pr =
                            mask + (size_t)(g1 * 64 + kbit[s]) * MW;
                        a0 |= pr[lane];
                        a1 |= (lane < MASKW - 64) ? pr[64 + lane] : 0ull;
                    }
                }
                while (t) {                         // >KSLOT overflow (rare)
                    const int b = __builtin_ctzll(t); t &= t - 1;
                    const unsigned long long* pr =
                        mask + (size_t)(g1 * 64 + b) * MW;
                    a0 |= pr[lane];
                    a1 |= (lane < MASKW - 64) ? pr[64 + lane] : 0ull;
                }
            }
            rem0 |= a0;
            rem1 |= a1;
        }
        d00 = n00; d01 = n01; d11 = n11;
    }

    __syncthreads();

    if (cnt < 300) {                                 // filler: unkept, asc index
        int c = cnt;
        for (int g = 0; g < MASKW && c < 300; ++g) {
            const unsigned long long valid =
                (g == MASKW - 1) ? 0x0000FFFFFFFFFFFFull : ~0ull;
            unsigned long long u = (~sKeepW[g]) & valid;
            while (u && c < 300) {
                const int b = __builtin_ctzll(u); u &= u - 1;
                if (lane == 0) sKept[c] = g * 64 + b;
                ++c;
            }
        }
    }
    __syncthreads();

    for (int s = lane; s < 300; s += 64) {
        const float4 b = sb[sKept[s]];
        out[s * 4 + 0] = b.x;
        out[s * 4 + 1] = b.y;
        out[s * 4 + 2] = b.z - b.x + 1.0f;
        out[s * 4 + 3] = b.w - b.y + 1.0f;
    }
}

// ---------------------------------------------------------------------------
extern "C" void kernel_launch(void* const* d_in, const int* in_sizes, int n_in,
                              void* d_out, int out_size, void* d_ws, size_t ws_size,
                              hipStream_t stream)
{
    (void)in_sizes; (void)n_in; (void)out_size; (void)ws_size;
    const float* x   = (const float*)d_in[0] + (size_t)7 * 512 * NPIX; // batch 7
    const float* cw3 = (const float*)d_in[1];
    const float* cb3 = (const float*)d_in[2];
    const float* rw  = (const float*)d_in[3];
    const float* rb  = (const float*)d_in[4];
    const float* clw = (const float*)d_in[5];
    const float* clb = (const float*)d_in[6];
    float* out = (float*)d_out;

    char* p = (char*)d_ws;
    auto alloc = [&](size_t n) { char* r = p; p += (n + 255) & ~(size_t)255; return r; };
    float*  part2  = (float*)alloc((size_t)CS * 512 * NPIX * 4);  // 41 MB
    float*  wtV    = (float*)alloc((size_t)4608 * 512 * 4);       // 9.4 MB
    float*  xpad   = (float*)alloc((size_t)512 * PSL * 4);        // 5.5 MB
    float*  feat   = (float*)alloc((size_t)512 * NPIX * 4);       // 5.12 MB
    float*  regcls = (float*)alloc((size_t)54 * NPIX * 4);        // 0.54 MB
    float4* boxes  = (float4*)alloc((size_t)NANCH * 16);          // 0.36 MB
    unsigned long long* keys = (unsigned long long*)alloc((size_t)NKEY * 8);
    int*    rank   = (int*)alloc((size_t)NANCH * 4);
    float4* sboxes = (float4*)alloc((size_t)PRE * 16);
    unsigned long long* mask = (unsigned long long*)alloc((size_t)PRE * MW * 8); // 4.6 MB

    prepK         <<<1088, 256, 0, stream>>>(x, cw3, xpad, wtV);
    conv3x3_v13   <<<dim3(64, 4, CS), 256, 0, stream>>>(xpad, wtV, part2);
    reduce_leaky4 <<<512, 256, 0, stream>>>(part2, cb3, feat);
    conv1x1_heads <<<dim3(40, 3, 3), 256, 0, stream>>>(feat, rw, rb, clw, clb, regcls);
    decodeK       <<<88, 256, 0, stream>>>(regcls, boxes, keys, rank);
    rankK         <<<dim3(88, 8), 256, 0, stream>>>(keys, rank);
    scatterK      <<<88, 256, 0, stream>>>(boxes, rank, sboxes);
    nmsMaskK      <<<dim3(375, 4), 256, 0, stream>>>(sboxes, mask);
    nmsScanOutK   <<<1, 64, 0, stream>>>(mask, sboxes, out);
}